// Round 3
// baseline (39539.099 us; speedup 1.0000x reference)
//
#include <hip/hip_runtime.h>
#include <hip/hip_cooperative_groups.h>
#include <math.h>

namespace cg = cooperative_groups;

#define B_ 128
#define T_ 512
#define I_ 128
#define H_ 1024
#define G4_ 4096
#define KE_ 1152  // I_ + H_

typedef short short8 __attribute__((ext_vector_type(8)));
typedef float f32x4 __attribute__((ext_vector_type(4)));

__device__ __forceinline__ float bf2f(unsigned short u){
  unsigned int x = ((unsigned int)u)<<16; float f; __builtin_memcpy(&f,&x,4); return f;
}
__device__ __forceinline__ unsigned short f2bf(float f){
  unsigned int x; __builtin_memcpy(&x,&f,4);
  x += 0x7fffu + ((x>>16)&1u);
  return (unsigned short)(x>>16);
}
__device__ __forceinline__ float sigm(float x){ return 1.f/(1.f+__expf(-x)); }
__device__ __forceinline__ float tanh_(float x){ return 1.f - 2.f/(1.f+__expf(2.f*x)); }

// ---------------- prepass kernels ----------------

__global__ void k_f32_to_bf16(const float* __restrict__ src, unsigned short* __restrict__ dst, int n){
  int i = blockIdx.x*256 + threadIdx.x;
  if(i < n) dst[i] = f2bf(src[i]);
}

__global__ void k_build_wcat(const float* __restrict__ Wih, const float* __restrict__ Whh,
                             unsigned short* __restrict__ out){
  int n = blockIdx.y;
  int k = blockIdx.x*256 + threadIdx.x;
  if(k < KE_){
    float v = (k < I_) ? Wih[n*I_ + k] : Whh[n*H_ + (k - I_)];
    out[n*KE_ + k] = f2bf(v);
  }
}

__global__ void k_build_weff(const float* __restrict__ Wih, const float* __restrict__ Whh,
                             const float* __restrict__ linW, unsigned short* __restrict__ out){
  int n = blockIdx.y;
  int k = blockIdx.x*256 + threadIdx.x;  // < 1024
  float acc = Whh[n*H_ + k];
  for(int j=0;j<I_;j++) acc += Wih[n*I_ + j] * linW[j*H_ + k];
  out[n*H_ + k] = f2bf(acc);
}

__global__ void k_build_bias(const float* __restrict__ ebih, const float* __restrict__ ebhh,
                             const float* __restrict__ dbih, const float* __restrict__ dbhh,
                             const float* __restrict__ dWih, const float* __restrict__ linb,
                             float* __restrict__ encb, float* __restrict__ decb, float* __restrict__ decbeff){
  int n = blockIdx.x*256 + threadIdx.x;  // < 4096
  encb[n] = ebih[n] + ebhh[n];
  float db = dbih[n] + dbhh[n];
  decb[n] = db;
  float acc = db;
  for(int j=0;j<I_;j++) acc += linb[j]*dWih[n*I_ + j];
  decbeff[n] = acc;
}

__global__ void k_init_h(unsigned short* __restrict__ h0){
  int i = blockIdx.x*256 + threadIdx.x;
  if(i < B_*H_) h0[i] = 0;
}

// ---------------- persistent kernel ----------------
// 256 blocks x 256 threads, cooperative. Block b: cc = b&63 owns h-cols
// [16cc,16cc+16) (and the 4 matching gate strips); rc = b>>6 owns batch rows
// [32rc,32rc+32). The 4 waves split K 4-way and reduce partials in LDS.
// c/h state lives in registers of waves 0-1 (fixed cell ownership all steps).

__device__ __forceinline__ void proj_tile(const unsigned short* __restrict__ hsrc,
    const unsigned short* __restrict__ linwbf, const float* __restrict__ linb,
    float* __restrict__ dout, int prb, int pcb, int w, int l, int tcol, f32x4 (*pred)[64])
{
  const int lr = l & 15, lq = l >> 4;
  f32x4 aco = (f32x4){0.f,0.f,0.f,0.f};
  #pragma unroll
  for(int ki=0; ki<8; ++ki){
    const int kb = (w*8 + ki)*32;
    short8 af = *(const short8*)(hsrc   + (prb+lr)*H_ + kb + lq*8);
    short8 bf = *(const short8*)(linwbf + (pcb+lr)*H_ + kb + lq*8);
    aco = __builtin_amdgcn_mfma_f32_16x16x32_bf16(af, bf, aco, 0,0,0);
  }
  pred[w][l] = aco;
  __syncthreads();
  if(w == 0){
    f32x4 s = pred[0][l] + pred[1][l] + pred[2][l] + pred[3][l];
    #pragma unroll
    for(int r=0;r<4;r++)
      dout[(long)(prb + lq*4 + r)*(T_*I_) + (long)tcol*I_ + pcb + lr] = s[r] + linb[pcb + lr];
  }
}

__global__ __launch_bounds__(256) void k_persist(
    const unsigned short* __restrict__ encW,   // [4096][1152] bf16
    const unsigned short* __restrict__ decW,   // [4096][1152] bf16
    const unsigned short* __restrict__ weffW,  // [4096][1024] bf16
    const unsigned short* __restrict__ xbf,    // [B][T][I] bf16
    unsigned short* __restrict__ h0buf,        // [B][H] bf16
    unsigned short* __restrict__ h1buf,        // [B][H] bf16
    const float* __restrict__ bias_enc,
    const float* __restrict__ bias_tf1,
    const float* __restrict__ bias_tf0,
    const int* __restrict__ lengths,
    const int* __restrict__ tfmask,
    const unsigned short* __restrict__ linwbf, // [128][1024] bf16
    const float* __restrict__ linb,
    float* __restrict__ dout)
{
  cg::grid_group grid = cg::this_grid();

  const int b   = blockIdx.x;      // 0..255
  const int cc  = b & 63;          // col chunk
  const int rc  = b >> 6;          // row chunk 0..3
  const int tid = threadIdx.x;
  const int w   = tid >> 6;        // wave 0..3 (K-slice)
  const int l   = tid & 63;
  const int lr  = l & 15;
  const int lq  = l >> 4;
  const int hc0 = cc * 16;
  const int hc  = hc0 + lr;
  const int am0 = rc*32 + lr;      // A rows for rowtile 0/1
  const int am1 = am0 + 16;

  __shared__ f32x4 red[4][2][4][64];   // [wave][rowtile][gate][lane]  32 KB
  __shared__ f32x4 pred[4][64];        // proj reduce                   4 KB

  int wrowA[4], wrowB[4];          // B-frag row bases, K=1152 / K=1024
  #pragma unroll
  for(int g=0; g<4; ++g){
    wrowA[g] = (g*H_ + hc0 + lr)*KE_ + lq*8;
    wrowB[g] = (g*H_ + hc0 + lr)*H_  + lq*8;
  }

  // proj assignment: blocks with (b&3)==0 handle out-tile b>>2 (64 tiles)
  const int isproj = ((b & 3) == 0);
  const int ptile  = b >> 2;
  const int prb = (ptile >> 3) * 16;
  const int pcb = (ptile & 7) * 16;

  // per-thread recurrent state (waves 0,1 own cells: row myrow0+r, col hc)
  const int myrow0 = rc*32 + w*16 + lq*4;
  float creg[4], hreg[4];
  int lenr[4];
  #pragma unroll
  for(int r=0; r<4; ++r){ creg[r]=0.f; hreg[r]=0.f; lenr[r]=0; }
  if(w < 2){
    #pragma unroll
    for(int r=0; r<4; ++r) lenr[r] = lengths[myrow0 + r];
  }

  for(int s=0; s<2*T_; ++s){
    const int dec = s >> 9;
    const int t   = s & (T_-1);
    const unsigned short* __restrict__ hread = (s & 1) ? h1buf : h0buf;
    unsigned short* __restrict__ hwrite      = (s & 1) ? h0buf : h1buf;

    f32x4 acc[2][4];
    #pragma unroll
    for(int rt=0; rt<2; ++rt)
      #pragma unroll
      for(int g=0; g<4; ++g) acc[rt][g] = (f32x4){0.f,0.f,0.f,0.f};

    const float* bias;
    const unsigned short* W;
    int kpath, xt = 0;
    if(dec == 0){ W = encW; bias = bias_enc; xt = t; kpath = 1; }
    else {
      const int tf = (t == 0) ? 1 : tfmask[t-1];
      if(tf){ W = decW; bias = bias_tf1; xt = (t==0)?(T_-1):(t-1); kpath = 1; }
      else  { W = weffW; bias = bias_tf0; kpath = 0; }
    }

    if(kpath){
      // K = 1152 = x(128) | h(1024); wave w owns kblocks [9w, 9w+9)
      if(w == 0){
        const unsigned short* xp0 = xbf + (long)am0*(T_*I_) + (long)xt*I_ + lq*8;
        const unsigned short* xp1 = xbf + (long)am1*(T_*I_) + (long)xt*I_ + lq*8;
        #pragma unroll
        for(int ki=0; ki<4; ++ki){
          const int kb = ki*32;
          const short8 a0 = *(const short8*)(xp0 + kb);
          const short8 a1 = *(const short8*)(xp1 + kb);
          #pragma unroll
          for(int g=0; g<4; ++g){
            const short8 bf = *(const short8*)(W + wrowA[g] + kb);
            acc[0][g] = __builtin_amdgcn_mfma_f32_16x16x32_bf16(a0, bf, acc[0][g], 0,0,0);
            acc[1][g] = __builtin_amdgcn_mfma_f32_16x16x32_bf16(a1, bf, acc[1][g], 0,0,0);
          }
        }
        const unsigned short* hp0 = hread + am0*H_ + lq*8;
        const unsigned short* hp1 = hread + am1*H_ + lq*8;
        #pragma unroll
        for(int ki=0; ki<5; ++ki){
          const int hk = ki*32;
          const int kb = I_ + hk;
          const short8 a0 = *(const short8*)(hp0 + hk);
          const short8 a1 = *(const short8*)(hp1 + hk);
          #pragma unroll
          for(int g=0; g<4; ++g){
            const short8 bf = *(const short8*)(W + wrowA[g] + kb);
            acc[0][g] = __builtin_amdgcn_mfma_f32_16x16x32_bf16(a0, bf, acc[0][g], 0,0,0);
            acc[1][g] = __builtin_amdgcn_mfma_f32_16x16x32_bf16(a1, bf, acc[1][g], 0,0,0);
          }
        }
      } else {
        const int k0 = w*288;
        const unsigned short* hp0 = hread + am0*H_ + lq*8 + (k0 - I_);
        const unsigned short* hp1 = hread + am1*H_ + lq*8 + (k0 - I_);
        #pragma unroll
        for(int ki=0; ki<9; ++ki){
          const int kk = ki*32;
          const int kb = k0 + kk;
          const short8 a0 = *(const short8*)(hp0 + kk);
          const short8 a1 = *(const short8*)(hp1 + kk);
          #pragma unroll
          for(int g=0; g<4; ++g){
            const short8 bf = *(const short8*)(W + wrowA[g] + kb);
            acc[0][g] = __builtin_amdgcn_mfma_f32_16x16x32_bf16(a0, bf, acc[0][g], 0,0,0);
            acc[1][g] = __builtin_amdgcn_mfma_f32_16x16x32_bf16(a1, bf, acc[1][g], 0,0,0);
          }
        }
      }
    } else {
      // K = 1024 (weff); wave w owns kblocks [8w, 8w+8)
      const int k0 = w*256;
      const unsigned short* hp0 = hread + am0*H_ + lq*8 + k0;
      const unsigned short* hp1 = hread + am1*H_ + lq*8 + k0;
      #pragma unroll
      for(int ki=0; ki<8; ++ki){
        const int kk = ki*32;
        const int kb = k0 + kk;
        const short8 a0 = *(const short8*)(hp0 + kk);
        const short8 a1 = *(const short8*)(hp1 + kk);
        #pragma unroll
        for(int g=0; g<4; ++g){
          const short8 bf = *(const short8*)(W + wrowB[g] + kb);
          acc[0][g] = __builtin_amdgcn_mfma_f32_16x16x32_bf16(a0, bf, acc[0][g], 0,0,0);
          acc[1][g] = __builtin_amdgcn_mfma_f32_16x16x32_bf16(a1, bf, acc[1][g], 0,0,0);
        }
      }
    }

    // partials -> LDS
    #pragma unroll
    for(int rt=0; rt<2; ++rt)
      #pragma unroll
      for(int g=0; g<4; ++g)
        red[w][rt][g][l] = acc[rt][g];
    __syncthreads();

    // epilogue: waves 0,1 reduce 4 K-slices and update their cells
    if(w < 2){
      const float bI = bias[hc], bF = bias[H_+hc], bG = bias[2*H_+hc], bO = bias[3*H_+hc];
      f32x4 sg[4];
      #pragma unroll
      for(int g=0; g<4; ++g)
        sg[g] = red[0][w][g][l] + red[1][w][g][l] + red[2][w][g][l] + red[3][w][g][l];
      #pragma unroll
      for(int r=0; r<4; ++r){
        const int mm = myrow0 + r;
        const float gi = sg[0][r] + bI;
        const float gf = sg[1][r] + bF;
        const float gg = sg[2][r] + bG;
        const float go = sg[3][r] + bO;
        const float i_ = sigm(gi), f_ = sigm(gf), g_ = tanh_(gg), o_ = sigm(go);
        const float cp = creg[r];
        const float c2 = f_*cp + i_*g_;
        const float h2 = o_ * tanh_(c2);
        if(dec == 0){
          const int vm = (t < lenr[r]) ? 1 : 0;
          const float hn = vm ? h2 : hreg[r];
          creg[r] = vm ? c2 : cp;
          hreg[r] = hn;
          hwrite[mm*H_ + hc] = f2bf(hn);
          dout[(long)(B_*T_*I_) + (long)mm*(T_*H_) + (long)t*H_ + hc] = vm ? h2 : 0.f;
        } else {
          creg[r] = c2;
          hreg[r] = h2;
          hwrite[mm*H_ + hc] = f2bf(h2);
        }
      }
    }

    // decoder projection out_{t-1} (off the recurrence; 64 designated blocks)
    if(dec && t > 0 && isproj)
      proj_tile(hread, linwbf, linb, dout, prb, pcb, w, l, t-1, pred);

    grid.sync();
  }

  // final projection out_{T-1} from final decoder h (h0buf after step 1023)
  if(isproj)
    proj_tile(h0buf, linwbf, linb, dout, prb, pcb, w, l, T_-1, pred);
}

// ---------------- host ----------------

extern "C" void kernel_launch(void* const* d_in, const int* in_sizes, int n_in,
                              void* d_out, int out_size, void* d_ws, size_t ws_size,
                              hipStream_t stream) {
  const float* x       = (const float*)d_in[0];
  const float* eWih    = (const float*)d_in[1];
  const float* eWhh    = (const float*)d_in[2];
  const float* ebih    = (const float*)d_in[3];
  const float* ebhh    = (const float*)d_in[4];
  const float* dWih    = (const float*)d_in[5];
  const float* dWhh    = (const float*)d_in[6];
  const float* dbih    = (const float*)d_in[7];
  const float* dbhh    = (const float*)d_in[8];
  const float* linW    = (const float*)d_in[9];
  const float* linb    = (const float*)d_in[10];
  const int*   lengths = (const int*)d_in[11];
  const int*   tfmask  = (const int*)d_in[12];
  float* dout = (float*)d_out;

  char* ws = (char*)d_ws;
  size_t off = 0;
  auto alloc = [&](size_t bytes)->char*{ char* p = ws + off; off = (off + bytes + 255) & ~(size_t)255; return p; };
  unsigned short* xbf   = (unsigned short*)alloc((size_t)B_*T_*I_*2);
  unsigned short* encW  = (unsigned short*)alloc((size_t)G4_*KE_*2);
  unsigned short* decW  = (unsigned short*)alloc((size_t)G4_*KE_*2);
  unsigned short* weff  = (unsigned short*)alloc((size_t)G4_*H_*2);
  unsigned short* linwb = (unsigned short*)alloc((size_t)I_*H_*2);
  unsigned short* h0    = (unsigned short*)alloc((size_t)B_*H_*2);
  unsigned short* h1    = (unsigned short*)alloc((size_t)B_*H_*2);
  float*          encb  = (float*)alloc((size_t)G4_*4);
  float*          decb  = (float*)alloc((size_t)G4_*4);
  float*          decbe = (float*)alloc((size_t)G4_*4);

  // prepass
  k_f32_to_bf16<<<dim3((B_*T_*I_+255)/256), dim3(256), 0, stream>>>(x, xbf, B_*T_*I_);
  k_f32_to_bf16<<<dim3((I_*H_+255)/256),   dim3(256), 0, stream>>>(linW, linwb, I_*H_);
  k_build_wcat<<<dim3(5, G4_), dim3(256), 0, stream>>>(eWih, eWhh, encW);
  k_build_wcat<<<dim3(5, G4_), dim3(256), 0, stream>>>(dWih, dWhh, decW);
  k_build_weff<<<dim3(4, G4_), dim3(256), 0, stream>>>(dWih, dWhh, linW, weff);
  k_build_bias<<<dim3(16), dim3(256), 0, stream>>>(ebih, ebhh, dbih, dbhh, dWih, linb, encb, decb, decbe);
  k_init_h<<<dim3((B_*H_+255)/256), dim3(256), 0, stream>>>(h0);

  void* kargs[] = {
    (void*)&encW, (void*)&decW, (void*)&weff, (void*)&xbf,
    (void*)&h0, (void*)&h1,
    (void*)&encb, (void*)&decb, (void*)&decbe,
    (void*)&lengths, (void*)&tfmask,
    (void*)&linwb, (void*)&linb, (void*)&dout
  };
  hipLaunchCooperativeKernel((void*)k_persist, dim3(256), dim3(256), kargs, 0, stream);
}

// Round 5
// 11496.083 us; speedup vs baseline: 3.4394x; 3.4394x over previous
//
#include <hip/hip_runtime.h>
#include <math.h>

#define B_ 128
#define T_ 512
#define I_ 128
#define H_ 1024
#define G4_ 4096
#define KE_ 1152  // I_ + H_
#define NBLK 256
#define GRPBLK 64   // blocks per row-chunk barrier group

typedef short short8 __attribute__((ext_vector_type(8)));
typedef float f32x4 __attribute__((ext_vector_type(4)));

__device__ __forceinline__ float bf2f(unsigned short u){
  unsigned int x = ((unsigned int)u)<<16; float f; __builtin_memcpy(&f,&x,4); return f;
}
__device__ __forceinline__ unsigned short f2bf(float f){
  unsigned int x; __builtin_memcpy(&x,&f,4);
  x += 0x7fffu + ((x>>16)&1u);
  return (unsigned short)(x>>16);
}
__device__ __forceinline__ float sigm(float x){ return 1.f/(1.f+__expf(-x)); }
__device__ __forceinline__ float tanh_(float x){ return 1.f - 2.f/(1.f+__expf(2.f*x)); }

// ---- cross-XCD-coherent h access (bypass L1/L2, served at coherence point) ----
__device__ __forceinline__ short8 ldg_h(const unsigned short* p){
  short8 r;
  asm volatile("global_load_dwordx4 %0, %1, off sc0 sc1" : "=v"(r) : "v"(p));
  return r;
}
__device__ __forceinline__ void stg_h(unsigned short* p, unsigned int v){
  asm volatile("global_store_short %0, %1, off sc0 sc1" : : "v"(p), "v"(v) : "memory");
}
// wait for all outstanding VMEM (incl. asm loads the compiler can't track),
// and fence the scheduler so MFMAs can't hoist above it (rule #18).
__device__ __forceinline__ void wait_vm0(){
  asm volatile("s_waitcnt vmcnt(0)" ::: "memory");
  __builtin_amdgcn_sched_barrier(0);
}

// per-rowchunk grid barrier: monotonic counter, arrive+poll via device-scope
// RMW atomics (coherence-point-executed; cannot read stale local L2).
// Bounded spin: if coherence were broken we fail fast instead of hanging.
__device__ __forceinline__ void group_bar(unsigned int* cnt, unsigned int tgt){
  asm volatile("s_waitcnt vmcnt(0)" ::: "memory");   // drain asm h-stores (compiler-invisible)
  __syncthreads();                                    // all waves of block drained
  if(threadIdx.x == 0){
    atomicAdd(cnt, 1u);
    unsigned int guard = 0;
    while(atomicAdd(cnt, 0u) < tgt && ++guard < 65536u)
      __builtin_amdgcn_s_sleep(16);
  }
  __syncthreads();
}

// ---------------- prepass kernels ----------------

__global__ void k_f32_to_bf16(const float* __restrict__ src, unsigned short* __restrict__ dst, int n){
  int i = blockIdx.x*256 + threadIdx.x;
  if(i < n) dst[i] = f2bf(src[i]);
}

__global__ void k_build_wcat(const float* __restrict__ Wih, const float* __restrict__ Whh,
                             unsigned short* __restrict__ out){
  int n = blockIdx.y;
  int k = blockIdx.x*256 + threadIdx.x;
  if(k < KE_){
    float v = (k < I_) ? Wih[n*I_ + k] : Whh[n*H_ + (k - I_)];
    out[n*KE_ + k] = f2bf(v);
  }
}

__global__ void k_build_weff(const float* __restrict__ Wih, const float* __restrict__ Whh,
                             const float* __restrict__ linW, unsigned short* __restrict__ out){
  int n = blockIdx.y;
  int k = blockIdx.x*256 + threadIdx.x;  // < 1024
  float acc = Whh[n*H_ + k];
  for(int j=0;j<I_;j++) acc += Wih[n*I_ + j] * linW[j*H_ + k];
  out[n*H_ + k] = f2bf(acc);
}

__global__ void k_build_bias(const float* __restrict__ ebih, const float* __restrict__ ebhh,
                             const float* __restrict__ dbih, const float* __restrict__ dbhh,
                             const float* __restrict__ dWih, const float* __restrict__ linb,
                             float* __restrict__ encb, float* __restrict__ decb, float* __restrict__ decbeff){
  int n = blockIdx.x*256 + threadIdx.x;  // < 4096
  encb[n] = ebih[n] + ebhh[n];
  float db = dbih[n] + dbhh[n];
  decb[n] = db;
  float acc = db;
  for(int j=0;j<I_;j++) acc += linb[j]*dWih[n*I_ + j];
  decbeff[n] = acc;
}

__global__ void k_init_h(unsigned short* __restrict__ h0, unsigned int* __restrict__ cnt){
  int i = blockIdx.x*256 + threadIdx.x;
  if(i < B_*H_) h0[i] = 0;
  if(i < 128) cnt[i] = 0u;   // 4 group counters (stride 32 uints) + padding
}

// ---------------- persistent kernel ----------------
// 256 blocks x 256 threads. Block b: cc = b&63 owns h-cols [16cc,16cc+16) and
// the 4 matching gate strips; rc = b>>6 owns batch rows [32rc,32rc+32).
// h exchange is confined within a row-chunk, so the inter-step barrier is 4
// independent 64-block barriers. h crosses XCDs via sc0/sc1 accesses; weights
// stay normally cached (L2 never invalidated -> L2-resident across steps).

__device__ __forceinline__ void proj_tile(const unsigned short* __restrict__ hsrc,
    const unsigned short* __restrict__ linwbf, const float* __restrict__ linb,
    float* __restrict__ dout, int prb, int pcb, int w, int l, int tcol, f32x4 (*pred)[64])
{
  const int lr = l & 15, lq = l >> 4;
  short8 afs[8];
  #pragma unroll
  for(int ki=0; ki<8; ++ki)
    afs[ki] = ldg_h(hsrc + (prb+lr)*H_ + (w*8+ki)*32 + lq*8);
  wait_vm0();
  f32x4 aco = (f32x4){0.f,0.f,0.f,0.f};
  #pragma unroll
  for(int ki=0; ki<8; ++ki){
    const short8 bf = *(const short8*)(linwbf + (pcb+lr)*H_ + (w*8+ki)*32 + lq*8);
    aco = __builtin_amdgcn_mfma_f32_16x16x32_bf16(afs[ki], bf, aco, 0,0,0);
  }
  pred[w][l] = aco;
  __syncthreads();
  if(w == 0){
    f32x4 s = pred[0][l] + pred[1][l] + pred[2][l] + pred[3][l];
    #pragma unroll
    for(int r=0;r<4;r++)
      dout[(long)(prb + lq*4 + r)*(T_*I_) + (long)tcol*I_ + pcb + lr] = s[r] + linb[pcb + lr];
  }
}

__global__ __launch_bounds__(256) void k_persist(
    const unsigned short* __restrict__ encW,   // [4096][1152] bf16
    const unsigned short* __restrict__ decW,   // [4096][1152] bf16
    const unsigned short* __restrict__ weffW,  // [4096][1024] bf16
    const unsigned short* __restrict__ xbf,    // [B][T][I] bf16
    unsigned short* __restrict__ h0buf,        // [B][H] bf16
    unsigned short* __restrict__ h1buf,        // [B][H] bf16
    const float* __restrict__ bias_enc,
    const float* __restrict__ bias_tf1,
    const float* __restrict__ bias_tf0,
    const int* __restrict__ lengths,
    const int* __restrict__ tfmask,
    const unsigned short* __restrict__ linwbf, // [128][1024] bf16
    const float* __restrict__ linb,
    float* __restrict__ dout,
    unsigned int* __restrict__ barcnt)
{
  const int b   = blockIdx.x;      // 0..255
  const int cc  = b & 63;          // col chunk
  const int rc  = b >> 6;          // row chunk 0..3
  const int tid = threadIdx.x;
  const int w   = tid >> 6;        // wave 0..3 (K-slice)
  const int l   = tid & 63;
  const int lr  = l & 15;
  const int lq  = l >> 4;
  const int hc0 = cc * 16;
  const int hc  = hc0 + lr;
  const int am0 = rc*32 + lr;      // A rows for rowtile 0/1
  const int am1 = am0 + 16;

  unsigned int* mycnt = barcnt + rc*32;   // 128B-spaced per-group counters

  __shared__ f32x4 red[4][2][4][64];   // [wave][rowtile][gate][lane]  32 KB
  __shared__ f32x4 pred[4][64];        // proj reduce                   4 KB

  int wrowA[4], wrowB[4];          // B-frag row bases, K=1152 / K=1024
  #pragma unroll
  for(int g=0; g<4; ++g){
    wrowA[g] = (g*H_ + hc0 + lr)*KE_ + lq*8;
    wrowB[g] = (g*H_ + hc0 + lr)*H_  + lq*8;
  }

  // proj assignment: blocks with (b&3)==0 handle out-tile b>>2 (64 tiles).
  // prb = (b>>5)*16 lies inside this block's own row-chunk.
  const int isproj = ((b & 3) == 0);
  const int ptile  = b >> 2;
  const int prb = (ptile >> 3) * 16;
  const int pcb = (ptile & 7) * 16;

  // per-thread recurrent state (waves 0,1 own cells: row myrow0+r, col hc)
  const int myrow0 = rc*32 + w*16 + lq*4;
  float creg[4], hreg[4];
  int lenr[4];
  #pragma unroll
  for(int r=0; r<4; ++r){ creg[r]=0.f; hreg[r]=0.f; lenr[r]=0; }
  if(w < 2){
    #pragma unroll
    for(int r=0; r<4; ++r) lenr[r] = lengths[myrow0 + r];
  }

  for(int s=0; s<2*T_; ++s){
    const int dec = s >> 9;
    const int t   = s & (T_-1);
    const unsigned short* __restrict__ hread = (s & 1) ? h1buf : h0buf;
    unsigned short* __restrict__ hwrite      = (s & 1) ? h0buf : h1buf;

    f32x4 acc[2][4];
    #pragma unroll
    for(int rt=0; rt<2; ++rt)
      #pragma unroll
      for(int g=0; g<4; ++g) acc[rt][g] = (f32x4){0.f,0.f,0.f,0.f};

    const float* bias;
    const unsigned short* W;
    int kpath, xt = 0;
    if(dec == 0){ W = encW; bias = bias_enc; xt = t; kpath = 1; }
    else {
      const int tf = (t == 0) ? 1 : tfmask[t-1];
      if(tf){ W = decW; bias = bias_tf1; xt = (t==0)?(T_-1):(t-1); kpath = 1; }
      else  { W = weffW; bias = bias_tf0; kpath = 0; }
    }

    if(kpath){
      // K = 1152 = x(128) | h(1024); wave w owns kblocks [9w, 9w+9)
      if(w == 0){
        // issue h loads first (coherence-point latency), overlap with x part
        const unsigned short* hp0 = hread + am0*H_ + lq*8;
        const unsigned short* hp1 = hread + am1*H_ + lq*8;
        short8 h0s[5], h1s[5];
        #pragma unroll
        for(int ki=0; ki<5; ++ki){
          h0s[ki] = ldg_h(hp0 + ki*32);
          h1s[ki] = ldg_h(hp1 + ki*32);
        }
        // x part (normal cached loads)
        const unsigned short* xp0 = xbf + (long)am0*(T_*I_) + (long)xt*I_ + lq*8;
        const unsigned short* xp1 = xbf + (long)am1*(T_*I_) + (long)xt*I_ + lq*8;
        #pragma unroll
        for(int ki=0; ki<4; ++ki){
          const int kb = ki*32;
          const short8 a0 = *(const short8*)(xp0 + kb);
          const short8 a1 = *(const short8*)(xp1 + kb);
          #pragma unroll
          for(int g=0; g<4; ++g){
            const short8 bf = *(const short8*)(W + wrowA[g] + kb);
            acc[0][g] = __builtin_amdgcn_mfma_f32_16x16x32_bf16(a0, bf, acc[0][g], 0,0,0);
            acc[1][g] = __builtin_amdgcn_mfma_f32_16x16x32_bf16(a1, bf, acc[1][g], 0,0,0);
          }
        }
        wait_vm0();
        #pragma unroll
        for(int ki=0; ki<5; ++ki){
          const int kb = I_ + ki*32;
          #pragma unroll
          for(int g=0; g<4; ++g){
            const short8 bf = *(const short8*)(W + wrowA[g] + kb);
            acc[0][g] = __builtin_amdgcn_mfma_f32_16x16x32_bf16(h0s[ki], bf, acc[0][g], 0,0,0);
            acc[1][g] = __builtin_amdgcn_mfma_f32_16x16x32_bf16(h1s[ki], bf, acc[1][g], 0,0,0);
          }
        }
      } else {
        const int k0 = w*288;
        const unsigned short* hp0 = hread + am0*H_ + lq*8 + (k0 - I_);
        const unsigned short* hp1 = hread + am1*H_ + lq*8 + (k0 - I_);
        short8 h0s[9], h1s[9];
        #pragma unroll
        for(int ki=0; ki<9; ++ki){
          h0s[ki] = ldg_h(hp0 + ki*32);
          h1s[ki] = ldg_h(hp1 + ki*32);
        }
        wait_vm0();
        #pragma unroll
        for(int ki=0; ki<9; ++ki){
          const int kb = k0 + ki*32;
          #pragma unroll
          for(int g=0; g<4; ++g){
            const short8 bf = *(const short8*)(W + wrowA[g] + kb);
            acc[0][g] = __builtin_amdgcn_mfma_f32_16x16x32_bf16(h0s[ki], bf, acc[0][g], 0,0,0);
            acc[1][g] = __builtin_amdgcn_mfma_f32_16x16x32_bf16(h1s[ki], bf, acc[1][g], 0,0,0);
          }
        }
      }
    } else {
      // K = 1024 (weff); wave w owns kblocks [8w, 8w+8)
      const int k0 = w*256;
      const unsigned short* hp0 = hread + am0*H_ + lq*8 + k0;
      const unsigned short* hp1 = hread + am1*H_ + lq*8 + k0;
      short8 h0s[8], h1s[8];
      #pragma unroll
      for(int ki=0; ki<8; ++ki){
        h0s[ki] = ldg_h(hp0 + ki*32);
        h1s[ki] = ldg_h(hp1 + ki*32);
      }
      wait_vm0();
      #pragma unroll
      for(int ki=0; ki<8; ++ki){
        const int kb = k0 + ki*32;
        #pragma unroll
        for(int g=0; g<4; ++g){
          const short8 bf = *(const short8*)(W + wrowB[g] + kb);
          acc[0][g] = __builtin_amdgcn_mfma_f32_16x16x32_bf16(h0s[ki], bf, acc[0][g], 0,0,0);
          acc[1][g] = __builtin_amdgcn_mfma_f32_16x16x32_bf16(h1s[ki], bf, acc[1][g], 0,0,0);
        }
      }
    }

    // partials -> LDS
    #pragma unroll
    for(int rt=0; rt<2; ++rt)
      #pragma unroll
      for(int g=0; g<4; ++g)
        red[w][rt][g][l] = acc[rt][g];
    __syncthreads();

    // epilogue: waves 0,1 reduce 4 K-slices and update their cells
    if(w < 2){
      const float bI = bias[hc], bF = bias[H_+hc], bG = bias[2*H_+hc], bO = bias[3*H_+hc];
      f32x4 sg[4];
      #pragma unroll
      for(int g=0; g<4; ++g)
        sg[g] = red[0][w][g][l] + red[1][w][g][l] + red[2][w][g][l] + red[3][w][g][l];
      #pragma unroll
      for(int r=0; r<4; ++r){
        const int mm = myrow0 + r;
        const float gi = sg[0][r] + bI;
        const float gf = sg[1][r] + bF;
        const float gg = sg[2][r] + bG;
        const float go = sg[3][r] + bO;
        const float i_ = sigm(gi), f_ = sigm(gf), g_ = tanh_(gg), o_ = sigm(go);
        const float cp = creg[r];
        const float c2 = f_*cp + i_*g_;
        const float h2 = o_ * tanh_(c2);
        if(dec == 0){
          const int vm = (t < lenr[r]) ? 1 : 0;
          const float hn = vm ? h2 : hreg[r];
          creg[r] = vm ? c2 : cp;
          hreg[r] = hn;
          stg_h(hwrite + mm*H_ + hc, (unsigned int)f2bf(hn));
          dout[(long)(B_*T_*I_) + (long)mm*(T_*H_) + (long)t*H_ + hc] = vm ? h2 : 0.f;
        } else {
          creg[r] = c2;
          hreg[r] = h2;
          stg_h(hwrite + mm*H_ + hc, (unsigned int)f2bf(h2));
        }
      }
    }

    // decoder projection out_{t-1} (own-rowchunk h; 64 designated blocks)
    if(dec && t > 0 && isproj)
      proj_tile(hread, linwbf, linb, dout, prb, pcb, w, l, t-1, pred);

    group_bar(mycnt, (unsigned)(s+1) * (unsigned)GRPBLK);
  }

  // final projection out_{T-1} from final decoder h (h0buf after step 1023)
  if(isproj)
    proj_tile(h0buf, linwbf, linb, dout, prb, pcb, w, l, T_-1, pred);
}

// ---------------- host ----------------

extern "C" void kernel_launch(void* const* d_in, const int* in_sizes, int n_in,
                              void* d_out, int out_size, void* d_ws, size_t ws_size,
                              hipStream_t stream) {
  const float* x       = (const float*)d_in[0];
  const float* eWih    = (const float*)d_in[1];
  const float* eWhh    = (const float*)d_in[2];
  const float* ebih    = (const float*)d_in[3];
  const float* ebhh    = (const float*)d_in[4];
  const float* dWih    = (const float*)d_in[5];
  const float* dWhh    = (const float*)d_in[6];
  const float* dbih    = (const float*)d_in[7];
  const float* dbhh    = (const float*)d_in[8];
  const float* linW    = (const float*)d_in[9];
  const float* linb    = (const float*)d_in[10];
  const int*   lengths = (const int*)d_in[11];
  const int*   tfmask  = (const int*)d_in[12];
  float* dout = (float*)d_out;

  char* ws = (char*)d_ws;
  size_t off = 0;
  auto alloc = [&](size_t bytes)->char*{ char* p = ws + off; off = (off + bytes + 255) & ~(size_t)255; return p; };
  unsigned short* xbf   = (unsigned short*)alloc((size_t)B_*T_*I_*2);
  unsigned short* encW  = (unsigned short*)alloc((size_t)G4_*KE_*2);
  unsigned short* decW  = (unsigned short*)alloc((size_t)G4_*KE_*2);
  unsigned short* weff  = (unsigned short*)alloc((size_t)G4_*H_*2);
  unsigned short* linwb = (unsigned short*)alloc((size_t)I_*H_*2);
  unsigned short* h0    = (unsigned short*)alloc((size_t)B_*H_*2);
  unsigned short* h1    = (unsigned short*)alloc((size_t)B_*H_*2);
  float*          encb  = (float*)alloc((size_t)G4_*4);
  float*          decb  = (float*)alloc((size_t)G4_*4);
  float*          decbe = (float*)alloc((size_t)G4_*4);
  unsigned int*   cnt   = (unsigned int*)alloc(512);

  // prepass
  k_f32_to_bf16<<<dim3((B_*T_*I_+255)/256), dim3(256), 0, stream>>>(x, xbf, B_*T_*I_);
  k_f32_to_bf16<<<dim3((I_*H_+255)/256),   dim3(256), 0, stream>>>(linW, linwb, I_*H_);
  k_build_wcat<<<dim3(5, G4_), dim3(256), 0, stream>>>(eWih, eWhh, encW);
  k_build_wcat<<<dim3(5, G4_), dim3(256), 0, stream>>>(dWih, dWhh, decW);
  k_build_weff<<<dim3(4, G4_), dim3(256), 0, stream>>>(dWih, dWhh, linW, weff);
  k_build_bias<<<dim3(16), dim3(256), 0, stream>>>(ebih, ebhh, dbih, dbhh, dWih, linb, encb, decb, decbe);
  k_init_h<<<dim3((B_*H_+255)/256), dim3(256), 0, stream>>>(h0, cnt);

  void* kargs[] = {
    (void*)&encW, (void*)&decW, (void*)&weff, (void*)&xbf,
    (void*)&h0, (void*)&h1,
    (void*)&encb, (void*)&decb, (void*)&decbe,
    (void*)&lengths, (void*)&tfmask,
    (void*)&linwb, (void*)&linb, (void*)&dout, (void*)&cnt
  };
  hipLaunchCooperativeKernel((void*)k_persist, dim3(NBLK), dim3(256), kargs, 0, stream);
}

// Round 6
// 10684.082 us; speedup vs baseline: 3.7007x; 1.0760x over previous
//
#include <hip/hip_runtime.h>
#include <math.h>

#define B_ 128
#define T_ 512
#define I_ 128
#define H_ 1024
#define G4_ 4096
#define KE_ 1152  // I_ + H_
#define NBLK 256
#define GRPBLK 64   // blocks per row-chunk barrier group

typedef short short8 __attribute__((ext_vector_type(8)));
typedef float f32x4 __attribute__((ext_vector_type(4)));

__device__ __forceinline__ float bf2f(unsigned short u){
  unsigned int x = ((unsigned int)u)<<16; float f; __builtin_memcpy(&f,&x,4); return f;
}
__device__ __forceinline__ unsigned short f2bf(float f){
  unsigned int x; __builtin_memcpy(&x,&f,4);
  x += 0x7fffu + ((x>>16)&1u);
  return (unsigned short)(x>>16);
}
__device__ __forceinline__ float sigm(float x){ return 1.f/(1.f+__expf(-x)); }
__device__ __forceinline__ float tanh_(float x){ return 1.f - 2.f/(1.f+__expf(2.f*x)); }

// ---- cross-XCD-coherent access (bypass L1/L2, served at coherence point) ----
// Round-5 hardware proof: sc0/sc1 loads correctly observe remote sc0/sc1
// stores (1024 dependent h-exchange steps passed exactly).
__device__ __forceinline__ short8 ldg_h(const unsigned short* p){
  short8 r;
  asm volatile("global_load_dwordx4 %0, %1, off sc0 sc1" : "=v"(r) : "v"(p));
  return r;
}
__device__ __forceinline__ void stg_h(unsigned short* p, unsigned int v){
  asm volatile("global_store_short %0, %1, off sc0 sc1" : : "v"(p), "v"(v) : "memory");
}
__device__ __forceinline__ unsigned int ldg_u32(const unsigned int* p){
  unsigned int r;
  asm volatile("global_load_dword %0, %1, off sc0 sc1" : "=v"(r) : "v"(p));
  asm volatile("s_waitcnt vmcnt(0)" ::: "memory");
  return r;
}
__device__ __forceinline__ void stg_u32(unsigned int* p, unsigned int v){
  asm volatile("global_store_dword %0, %1, off sc0 sc1" : : "v"(p), "v"(v) : "memory");
}
// wait for all outstanding VMEM (incl. asm loads the compiler can't track),
// and fence the scheduler so MFMAs can't hoist above it (rule #18).
__device__ __forceinline__ void wait_vm0(){
  asm volatile("s_waitcnt vmcnt(0)" ::: "memory");
  __builtin_amdgcn_sched_barrier(0);
}

// per-rowchunk grid barrier, READ-POLLING (no RMW contention):
// each block sc-stores s+1 to its flag slot; group leader's wave 0 scans the
// 64 flags with one coalesced 64-lane sc load + __all, then sc-stores the
// group generation; non-leaders poll the generation with sc loads.
// Bounded spins: on coherence failure we fail fast (absmax) instead of hanging.
__device__ __forceinline__ void group_bar(unsigned int* flags, unsigned int* gen,
                                          int isleader, int myflag,
                                          unsigned int tgt, int w, int l){
  asm volatile("s_waitcnt vmcnt(0)" ::: "memory");   // h stores ack'd at MALL
  __syncthreads();                                    // all waves of block drained
  if(w == 0){
    if(l == 0) stg_u32(flags + myflag, tgt);          // publish arrival
    if(isleader){
      unsigned int guard = 0;
      for(;;){
        unsigned int f = ldg_u32(flags + l);          // 64 lanes, coalesced
        if(__all((int)(f >= tgt))) break;
        if(++guard >= (1u<<17)) break;
        __builtin_amdgcn_s_sleep(1);
      }
      if(l == 0) stg_u32(gen, tgt);                   // release group
    } else if(l == 0){
      unsigned int guard = 0;
      while(ldg_u32(gen) < tgt && ++guard < (1u<<17))
        __builtin_amdgcn_s_sleep(1);
    }
  }
  __syncthreads();
}

// ---------------- prepass kernels ----------------

__global__ void k_f32_to_bf16(const float* __restrict__ src, unsigned short* __restrict__ dst, int n){
  int i = blockIdx.x*256 + threadIdx.x;
  if(i < n) dst[i] = f2bf(src[i]);
}

__global__ void k_build_wcat(const float* __restrict__ Wih, const float* __restrict__ Whh,
                             unsigned short* __restrict__ out){
  int n = blockIdx.y;
  int k = blockIdx.x*256 + threadIdx.x;
  if(k < KE_){
    float v = (k < I_) ? Wih[n*I_ + k] : Whh[n*H_ + (k - I_)];
    out[n*KE_ + k] = f2bf(v);
  }
}

__global__ void k_build_weff(const float* __restrict__ Wih, const float* __restrict__ Whh,
                             const float* __restrict__ linW, unsigned short* __restrict__ out){
  int n = blockIdx.y;
  int k = blockIdx.x*256 + threadIdx.x;  // < 1024
  float acc = Whh[n*H_ + k];
  for(int j=0;j<I_;j++) acc += Wih[n*I_ + j] * linW[j*H_ + k];
  out[n*H_ + k] = f2bf(acc);
}

__global__ void k_build_bias(const float* __restrict__ ebih, const float* __restrict__ ebhh,
                             const float* __restrict__ dbih, const float* __restrict__ dbhh,
                             const float* __restrict__ dWih, const float* __restrict__ linb,
                             float* __restrict__ encb, float* __restrict__ decb, float* __restrict__ decbeff){
  int n = blockIdx.x*256 + threadIdx.x;  // < 4096
  encb[n] = ebih[n] + ebhh[n];
  float db = dbih[n] + dbhh[n];
  decb[n] = db;
  float acc = db;
  for(int j=0;j<I_;j++) acc += linb[j]*dWih[n*I_ + j];
  decbeff[n] = acc;
}

__global__ void k_init_h(unsigned short* __restrict__ h0, unsigned int* __restrict__ cnt){
  int i = blockIdx.x*256 + threadIdx.x;
  if(i < B_*H_) h0[i] = 0;
  if(i < 512) cnt[i] = 0u;   // 4 groups x (64 flags + pad + gen)
}

// ---------------- persistent kernel ----------------
// 256 blocks x 256 threads. Block b: cc = b&63 owns h-cols [16cc,16cc+16) and
// the 4 matching gate strips; rc = b>>6 owns batch rows [32rc,32rc+32).
// h exchange is confined within a row-chunk -> 4 independent 64-block
// barriers. h crosses XCDs via sc0/sc1 accesses; weights stay normally
// cached (L2 never invalidated -> L2-resident across steps).

__device__ __forceinline__ void proj_tile(const unsigned short* __restrict__ hsrc,
    const unsigned short* __restrict__ linwbf, const float* __restrict__ linb,
    float* __restrict__ dout, int prb, int pcb, int w, int l, int tcol, f32x4 (*pred)[64])
{
  const int lr = l & 15, lq = l >> 4;
  short8 afs[8];
  #pragma unroll
  for(int ki=0; ki<8; ++ki)
    afs[ki] = ldg_h(hsrc + (prb+lr)*H_ + (w*8+ki)*32 + lq*8);
  wait_vm0();
  f32x4 aco = (f32x4){0.f,0.f,0.f,0.f};
  #pragma unroll
  for(int ki=0; ki<8; ++ki){
    const short8 bf = *(const short8*)(linwbf + (pcb+lr)*H_ + (w*8+ki)*32 + lq*8);
    aco = __builtin_amdgcn_mfma_f32_16x16x32_bf16(afs[ki], bf, aco, 0,0,0);
  }
  pred[w][l] = aco;
  __syncthreads();
  if(w == 0){
    f32x4 s = pred[0][l] + pred[1][l] + pred[2][l] + pred[3][l];
    #pragma unroll
    for(int r=0;r<4;r++)
      dout[(long)(prb + lq*4 + r)*(T_*I_) + (long)tcol*I_ + pcb + lr] = s[r] + linb[pcb + lr];
  }
}

__global__ __launch_bounds__(256) void k_persist(
    const unsigned short* __restrict__ encW,   // [4096][1152] bf16
    const unsigned short* __restrict__ decW,   // [4096][1152] bf16
    const unsigned short* __restrict__ weffW,  // [4096][1024] bf16
    const unsigned short* __restrict__ xbf,    // [B][T][I] bf16
    unsigned short* __restrict__ h0buf,        // [B][H] bf16
    unsigned short* __restrict__ h1buf,        // [B][H] bf16
    const float* __restrict__ bias_enc,
    const float* __restrict__ bias_tf1,
    const float* __restrict__ bias_tf0,
    const int* __restrict__ lengths,
    const int* __restrict__ tfmask,
    const unsigned short* __restrict__ linwbf, // [128][1024] bf16
    const float* __restrict__ linb,
    float* __restrict__ dout,
    unsigned int* __restrict__ barcnt)
{
  const int b   = blockIdx.x;      // 0..255
  const int cc  = b & 63;          // col chunk
  const int rc  = b >> 6;          // row chunk 0..3
  const int tid = threadIdx.x;
  const int w   = tid >> 6;        // wave 0..3 (K-slice)
  const int l   = tid & 63;
  const int lr  = l & 15;
  const int lq  = l >> 4;
  const int hc0 = cc * 16;
  const int hc  = hc0 + lr;
  const int am0 = rc*32 + lr;      // A rows for rowtile 0/1
  const int am1 = am0 + 16;

  // barrier slots for this row-chunk group: 64 flags + gen (separate line)
  unsigned int* gflags = barcnt + rc*128;
  unsigned int* ggen   = gflags + 96;
  const int isleader = (cc == 0);

  __shared__ f32x4 red[4][2][4][64];   // [wave][rowtile][gate][lane]  32 KB
  __shared__ f32x4 pred[4][64];        // proj reduce                   4 KB

  int wrowA[4], wrowB[4];          // B-frag row bases, K=1152 / K=1024
  #pragma unroll
  for(int g=0; g<4; ++g){
    wrowA[g] = (g*H_ + hc0 + lr)*KE_ + lq*8;
    wrowB[g] = (g*H_ + hc0 + lr)*H_  + lq*8;
  }

  // proj assignment: blocks with (b&3)==0 handle out-tile b>>2 (64 tiles).
  // prb = (b>>5)*16 lies inside this block's own row-chunk.
  const int isproj = ((b & 3) == 0);
  const int ptile  = b >> 2;
  const int prb = (ptile >> 3) * 16;
  const int pcb = (ptile & 7) * 16;

  // per-thread recurrent state (waves 0,1 own cells: row myrow0+r, col hc)
  const int myrow0 = rc*32 + w*16 + lq*4;
  float creg[4], hreg[4];
  int lenr[4];
  #pragma unroll
  for(int r=0; r<4; ++r){ creg[r]=0.f; hreg[r]=0.f; lenr[r]=0; }
  if(w < 2){
    #pragma unroll
    for(int r=0; r<4; ++r) lenr[r] = lengths[myrow0 + r];
  }

  for(int s=0; s<2*T_; ++s){
    const int dec = s >> 9;
    const int t   = s & (T_-1);
    const unsigned short* __restrict__ hread = (s & 1) ? h1buf : h0buf;
    unsigned short* __restrict__ hwrite      = (s & 1) ? h0buf : h1buf;

    f32x4 acc[2][4];
    #pragma unroll
    for(int rt=0; rt<2; ++rt)
      #pragma unroll
      for(int g=0; g<4; ++g) acc[rt][g] = (f32x4){0.f,0.f,0.f,0.f};

    const float* bias;
    const unsigned short* W;
    int kpath, xt = 0;
    if(dec == 0){ W = encW; bias = bias_enc; xt = t; kpath = 1; }
    else {
      const int tf = (t == 0) ? 1 : tfmask[t-1];
      if(tf){ W = decW; bias = bias_tf1; xt = (t==0)?(T_-1):(t-1); kpath = 1; }
      else  { W = weffW; bias = bias_tf0; kpath = 0; }
    }

    if(kpath){
      // K = 1152 = x(128) | h(1024); wave w owns kblocks [9w, 9w+9)
      if(w == 0){
        // issue h loads first (coherence-point latency), overlap with x part
        const unsigned short* hp0 = hread + am0*H_ + lq*8;
        const unsigned short* hp1 = hread + am1*H_ + lq*8;
        short8 h0s[5], h1s[5];
        #pragma unroll
        for(int ki=0; ki<5; ++ki){
          h0s[ki] = ldg_h(hp0 + ki*32);
          h1s[ki] = ldg_h(hp1 + ki*32);
        }
        // x part (normal cached loads)
        const unsigned short* xp0 = xbf + (long)am0*(T_*I_) + (long)xt*I_ + lq*8;
        const unsigned short* xp1 = xbf + (long)am1*(T_*I_) + (long)xt*I_ + lq*8;
        #pragma unroll
        for(int ki=0; ki<4; ++ki){
          const int kb = ki*32;
          const short8 a0 = *(const short8*)(xp0 + kb);
          const short8 a1 = *(const short8*)(xp1 + kb);
          #pragma unroll
          for(int g=0; g<4; ++g){
            const short8 bf = *(const short8*)(W + wrowA[g] + kb);
            acc[0][g] = __builtin_amdgcn_mfma_f32_16x16x32_bf16(a0, bf, acc[0][g], 0,0,0);
            acc[1][g] = __builtin_amdgcn_mfma_f32_16x16x32_bf16(a1, bf, acc[1][g], 0,0,0);
          }
        }
        wait_vm0();
        #pragma unroll
        for(int ki=0; ki<5; ++ki){
          const int kb = I_ + ki*32;
          #pragma unroll
          for(int g=0; g<4; ++g){
            const short8 bf = *(const short8*)(W + wrowA[g] + kb);
            acc[0][g] = __builtin_amdgcn_mfma_f32_16x16x32_bf16(h0s[ki], bf, acc[0][g], 0,0,0);
            acc[1][g] = __builtin_amdgcn_mfma_f32_16x16x32_bf16(h1s[ki], bf, acc[1][g], 0,0,0);
          }
        }
      } else {
        const int k0 = w*288;
        const unsigned short* hp0 = hread + am0*H_ + lq*8 + (k0 - I_);
        const unsigned short* hp1 = hread + am1*H_ + lq*8 + (k0 - I_);
        short8 h0s[9], h1s[9];
        #pragma unroll
        for(int ki=0; ki<9; ++ki){
          h0s[ki] = ldg_h(hp0 + ki*32);
          h1s[ki] = ldg_h(hp1 + ki*32);
        }
        wait_vm0();
        #pragma unroll
        for(int ki=0; ki<9; ++ki){
          const int kb = k0 + ki*32;
          #pragma unroll
          for(int g=0; g<4; ++g){
            const short8 bf = *(const short8*)(W + wrowA[g] + kb);
            acc[0][g] = __builtin_amdgcn_mfma_f32_16x16x32_bf16(h0s[ki], bf, acc[0][g], 0,0,0);
            acc[1][g] = __builtin_amdgcn_mfma_f32_16x16x32_bf16(h1s[ki], bf, acc[1][g], 0,0,0);
          }
        }
      }
    } else {
      // K = 1024 (weff); wave w owns kblocks [8w, 8w+8)
      const int k0 = w*256;
      const unsigned short* hp0 = hread + am0*H_ + lq*8 + k0;
      const unsigned short* hp1 = hread + am1*H_ + lq*8 + k0;
      short8 h0s[8], h1s[8];
      #pragma unroll
      for(int ki=0; ki<8; ++ki){
        h0s[ki] = ldg_h(hp0 + ki*32);
        h1s[ki] = ldg_h(hp1 + ki*32);
      }
      wait_vm0();
      #pragma unroll
      for(int ki=0; ki<8; ++ki){
        const int kb = k0 + ki*32;
        #pragma unroll
        for(int g=0; g<4; ++g){
          const short8 bf = *(const short8*)(W + wrowB[g] + kb);
          acc[0][g] = __builtin_amdgcn_mfma_f32_16x16x32_bf16(h0s[ki], bf, acc[0][g], 0,0,0);
          acc[1][g] = __builtin_amdgcn_mfma_f32_16x16x32_bf16(h1s[ki], bf, acc[1][g], 0,0,0);
        }
      }
    }

    // partials -> LDS
    #pragma unroll
    for(int rt=0; rt<2; ++rt)
      #pragma unroll
      for(int g=0; g<4; ++g)
        red[w][rt][g][l] = acc[rt][g];
    __syncthreads();

    // epilogue: waves 0,1 reduce 4 K-slices and update their cells
    if(w < 2){
      const float bI = bias[hc], bF = bias[H_+hc], bG = bias[2*H_+hc], bO = bias[3*H_+hc];
      f32x4 sg[4];
      #pragma unroll
      for(int g=0; g<4; ++g)
        sg[g] = red[0][w][g][l] + red[1][w][g][l] + red[2][w][g][l] + red[3][w][g][l];
      #pragma unroll
      for(int r=0; r<4; ++r){
        const int mm = myrow0 + r;
        const float gi = sg[0][r] + bI;
        const float gf = sg[1][r] + bF;
        const float gg = sg[2][r] + bG;
        const float go = sg[3][r] + bO;
        const float i_ = sigm(gi), f_ = sigm(gf), g_ = tanh_(gg), o_ = sigm(go);
        const float cp = creg[r];
        const float c2 = f_*cp + i_*g_;
        const float h2 = o_ * tanh_(c2);
        if(dec == 0){
          const int vm = (t < lenr[r]) ? 1 : 0;
          const float hn = vm ? h2 : hreg[r];
          creg[r] = vm ? c2 : cp;
          hreg[r] = hn;
          stg_h(hwrite + mm*H_ + hc, (unsigned int)f2bf(hn));
          dout[(long)(B_*T_*I_) + (long)mm*(T_*H_) + (long)t*H_ + hc] = vm ? h2 : 0.f;
        } else {
          creg[r] = c2;
          hreg[r] = h2;
          stg_h(hwrite + mm*H_ + hc, (unsigned int)f2bf(h2));
        }
      }
    }

    // decoder projection out_{t-1} (own-rowchunk h; 64 designated blocks)
    if(dec && t > 0 && isproj)
      proj_tile(hread, linwbf, linb, dout, prb, pcb, w, l, t-1, pred);

    group_bar(gflags, ggen, isleader, cc, (unsigned)(s+1), w, l);
  }

  // final projection out_{T-1} from final decoder h (h0buf after step 1023)
  if(isproj)
    proj_tile(h0buf, linwbf, linb, dout, prb, pcb, w, l, T_-1, pred);
}

// ---------------- host ----------------

extern "C" void kernel_launch(void* const* d_in, const int* in_sizes, int n_in,
                              void* d_out, int out_size, void* d_ws, size_t ws_size,
                              hipStream_t stream) {
  const float* x       = (const float*)d_in[0];
  const float* eWih    = (const float*)d_in[1];
  const float* eWhh    = (const float*)d_in[2];
  const float* ebih    = (const float*)d_in[3];
  const float* ebhh    = (const float*)d_in[4];
  const float* dWih    = (const float*)d_in[5];
  const float* dWhh    = (const float*)d_in[6];
  const float* dbih    = (const float*)d_in[7];
  const float* dbhh    = (const float*)d_in[8];
  const float* linW    = (const float*)d_in[9];
  const float* linb    = (const float*)d_in[10];
  const int*   lengths = (const int*)d_in[11];
  const int*   tfmask  = (const int*)d_in[12];
  float* dout = (float*)d_out;

  char* ws = (char*)d_ws;
  size_t off = 0;
  auto alloc = [&](size_t bytes)->char*{ char* p = ws + off; off = (off + bytes + 255) & ~(size_t)255; return p; };
  unsigned short* xbf   = (unsigned short*)alloc((size_t)B_*T_*I_*2);
  unsigned short* encW  = (unsigned short*)alloc((size_t)G4_*KE_*2);
  unsigned short* decW  = (unsigned short*)alloc((size_t)G4_*KE_*2);
  unsigned short* weff  = (unsigned short*)alloc((size_t)G4_*H_*2);
  unsigned short* linwb = (unsigned short*)alloc((size_t)I_*H_*2);
  unsigned short* h0    = (unsigned short*)alloc((size_t)B_*H_*2);
  unsigned short* h1    = (unsigned short*)alloc((size_t)B_*H_*2);
  float*          encb  = (float*)alloc((size_t)G4_*4);
  float*          decb  = (float*)alloc((size_t)G4_*4);
  float*          decbe = (float*)alloc((size_t)G4_*4);
  unsigned int*   cnt   = (unsigned int*)alloc(2048);

  // prepass
  k_f32_to_bf16<<<dim3((B_*T_*I_+255)/256), dim3(256), 0, stream>>>(x, xbf, B_*T_*I_);
  k_f32_to_bf16<<<dim3((I_*H_+255)/256),   dim3(256), 0, stream>>>(linW, linwb, I_*H_);
  k_build_wcat<<<dim3(5, G4_), dim3(256), 0, stream>>>(eWih, eWhh, encW);
  k_build_wcat<<<dim3(5, G4_), dim3(256), 0, stream>>>(dWih, dWhh, decW);
  k_build_weff<<<dim3(4, G4_), dim3(256), 0, stream>>>(dWih, dWhh, linW, weff);
  k_build_bias<<<dim3(16), dim3(256), 0, stream>>>(ebih, ebhh, dbih, dbhh, dWih, linb, encb, decb, decbe);
  k_init_h<<<dim3((B_*H_+255)/256), dim3(256), 0, stream>>>(h0, cnt);

  void* kargs[] = {
    (void*)&encW, (void*)&decW, (void*)&weff, (void*)&xbf,
    (void*)&h0, (void*)&h1,
    (void*)&encb, (void*)&decb, (void*)&decbe,
    (void*)&lengths, (void*)&tfmask,
    (void*)&linwb, (void*)&linb, (void*)&dout, (void*)&cnt
  };
  hipLaunchCooperativeKernel((void*)k_persist, dim3(NBLK), dim3(256), kargs, 0, stream);
}